// Round 1
// baseline (471.615 us; speedup 1.0000x reference)
//
#include <hip/hip_runtime.h>

// Pipeline for XCA channel attention (B=8, C=192, HW=128x128, heads=4, ch=48):
//  k_init        : zero G + norm2 accumulators
//  k_conv_w      : qkv_w fp32 -> bf16 [576][192]
//  k_transpose_x : x [b][192][HW] fp32 -> xbT [b][HW][192] bf16 (NHWC, K-contig for MFMA B-frags)
//  k_qkv_gemm    : qkv[b] = Wqkv(576x192) @ x[b](192xHW), bf16 MFMA, out bf16 [b][576][HW]
//  k_dw          : depthwise 3x3 pad1 per channel; fused sum-of-squares for q,k channel norms
//  k_transpose_v : v channels -> vT [b][HW][192] bf16
//  k_gram        : G[b,h] = q @ k^T (48x48, K=HW), K-split across 16 blocks, MFMA + atomicAdd
//  k_softmax     : attn = softmax(G/(|q||k|) * temperature)
//  k_fold        : M_b = Wproj @ blockdiag(attn)  (192x192 per batch, fp32 -> bf16)
//  k_out_gemm    : out[b] = M_b @ v[b]  (fuses attn@v and proj conv), fp32 out

#define B_    8
#define C_    192
#define C3_   576
#define IMG_  128
#define HW_   16384
#define HEADS_ 4
#define CHD_  48

typedef short bfrag __attribute__((ext_vector_type(8)));
typedef float f4 __attribute__((ext_vector_type(4)));

__device__ __forceinline__ unsigned short f2bf(float f){
  unsigned int u = __builtin_bit_cast(unsigned int, f);
  u += 0x7fffu + ((u >> 16) & 1u);          // round-to-nearest-even
  return (unsigned short)(u >> 16);
}
__device__ __forceinline__ float bf2f(unsigned short h){
  unsigned int u = ((unsigned int)h) << 16;
  return __builtin_bit_cast(float, u);
}

// ---------------- init: zero G (8*4*48*48) + norm2 (8*384) ----------------
__global__ __launch_bounds__(256) void k_init(float* __restrict__ p, int n){
  int i = blockIdx.x*256 + threadIdx.x;
  if(i < n) p[i] = 0.f;
}

// ---------------- W conversion ----------------
__global__ __launch_bounds__(256) void k_conv_w(const float* __restrict__ w,
                                                unsigned short* __restrict__ o, int n){
  for(int i = blockIdx.x*256 + threadIdx.x; i < n; i += gridDim.x*256)
    o[i] = f2bf(w[i]);
}

// ---------------- x transpose: [b][192][HW] f32 -> [b][HW][192] bf16 ----------------
__global__ __launch_bounds__(256) void k_transpose_x(const float* __restrict__ x,
                                                     unsigned short* __restrict__ xbT){
  __shared__ float tile[64][65];
  const int nt = blockIdx.x & 255;
  const int cg = (blockIdx.x >> 8) % 3;
  const int b  = blockIdx.x / 768;
  const float* xp = x + ((size_t)(b*C_ + cg*64))*HW_ + nt*64;
  #pragma unroll
  for(int i=0;i<16;i++){
    int idx = threadIdx.x + (i<<8);
    int r = idx >> 6, cc = idx & 63;        // r = ch-local, cc = n-local
    tile[r][cc] = xp[(size_t)r*HW_ + cc];
  }
  __syncthreads();
  unsigned short* op = xbT + ((size_t)(b*HW_ + nt*64))*C_ + cg*64;
  #pragma unroll
  for(int i=0;i<16;i++){
    int idx = threadIdx.x + (i<<8);
    int r = idx >> 6, cc = idx & 63;        // r = n-local, cc = ch-local
    op[(size_t)r*C_ + cc] = f2bf(tile[cc][r]);
  }
}

// ---------------- qkv GEMM: D[oc][n] = W[oc][k] * xT[n][k] ----------------
__global__ __launch_bounds__(256) void k_qkv_gemm(const unsigned short* __restrict__ xbT,
                                                  const unsigned short* __restrict__ wb,
                                                  unsigned short* __restrict__ qkvb){
  __shared__ alignas(16) unsigned short xs[64][200];   // [pixel][k], pad->200 (stride=4 banks mod 32)
  __shared__ alignas(16) unsigned short wsl[64][200];  // [oc][k]
  const int nt = blockIdx.x & 255, b = blockIdx.x >> 8;
  const int t = threadIdx.x, lane = t & 63, wv = t >> 6;
  const unsigned short* xp = xbT + ((size_t)(b*HW_ + nt*64))*C_;
  #pragma unroll
  for(int i=0;i<6;i++){
    int idx = t + (i<<8);
    int r = idx/24, c8 = idx%24;
    *(bfrag*)&xs[r][c8*8] = *(const bfrag*)(xp + (size_t)r*C_ + c8*8);
  }
  const int g = lane >> 4, rr = lane & 15;
  for(int ct=0; ct<9; ct++){
    if(ct) __syncthreads();
    const unsigned short* wp = wb + (size_t)(ct*64)*C_;
    #pragma unroll
    for(int i=0;i<6;i++){
      int idx = t + (i<<8);
      int r = idx/24, c8 = idx%24;
      *(bfrag*)&wsl[r][c8*8] = *(const bfrag*)(wp + (size_t)r*C_ + c8*8);
    }
    __syncthreads();
    f4 acc0={0,0,0,0}, acc1={0,0,0,0}, acc2={0,0,0,0}, acc3={0,0,0,0};
    #pragma unroll
    for(int kk=0; kk<6; kk++){
      const int ko = kk*32 + g*8;
      bfrag a  = *(const bfrag*)&wsl[wv*16 + rr][ko];
      bfrag b0 = *(const bfrag*)&xs[ 0 + rr][ko];
      bfrag b1 = *(const bfrag*)&xs[16 + rr][ko];
      bfrag b2 = *(const bfrag*)&xs[32 + rr][ko];
      bfrag b3 = *(const bfrag*)&xs[48 + rr][ko];
      acc0 = __builtin_amdgcn_mfma_f32_16x16x32_bf16(a, b0, acc0, 0,0,0);
      acc1 = __builtin_amdgcn_mfma_f32_16x16x32_bf16(a, b1, acc1, 0,0,0);
      acc2 = __builtin_amdgcn_mfma_f32_16x16x32_bf16(a, b2, acc2, 0,0,0);
      acc3 = __builtin_amdgcn_mfma_f32_16x16x32_bf16(a, b3, acc3, 0,0,0);
    }
    // D: col = lane&15 (n), row = (lane>>4)*4 + reg (oc)
    unsigned short* op = qkvb + ((size_t)(b*C3_ + ct*64 + wv*16 + g*4))*HW_ + nt*64 + rr;
    #pragma unroll
    for(int r=0;r<4;r++){
      op[(size_t)r*HW_ +  0] = f2bf(acc0[r]);
      op[(size_t)r*HW_ + 16] = f2bf(acc1[r]);
      op[(size_t)r*HW_ + 32] = f2bf(acc2[r]);
      op[(size_t)r*HW_ + 48] = f2bf(acc3[r]);
    }
  }
}

// ---------------- depthwise 3x3, pad 1; fused q/k sum-of-squares ----------------
__global__ __launch_bounds__(256) void k_dw(const unsigned short* __restrict__ qkvb,
                                            const float* __restrict__ dww,
                                            unsigned short* __restrict__ dwb,
                                            float* __restrict__ norm2){
  __shared__ alignas(16) unsigned short pl[16384];
  const int c = blockIdx.x % C3_, b = blockIdx.x / C3_;
  const unsigned short* ip = qkvb + ((size_t)(b*C3_ + c))*HW_;
  const int t = threadIdx.x;
  #pragma unroll
  for(int i=0;i<8;i++){
    int e = (t + (i<<8)) << 3;
    *(bfrag*)&pl[e] = *(const bfrag*)(ip + e);
  }
  const float w0=dww[c*9+0], w1=dww[c*9+1], w2=dww[c*9+2],
              w3=dww[c*9+3], w4=dww[c*9+4], w5=dww[c*9+5],
              w6=dww[c*9+6], w7=dww[c*9+7], w8=dww[c*9+8];
  __syncthreads();
  float ssq = 0.f;
  unsigned short* op = dwb + ((size_t)(b*C3_ + c))*HW_;
  for(int i=0;i<64;i++){
    int p = t + (i<<8);
    int y = p >> 7, x = p & 127;
    float s = w4 * bf2f(pl[p]);
    bool xl = (x > 0), xr = (x < 127);
    if(xl) s += w3 * bf2f(pl[p-1]);
    if(xr) s += w5 * bf2f(pl[p+1]);
    if(y > 0){
      s += w1 * bf2f(pl[p-128]);
      if(xl) s += w0 * bf2f(pl[p-129]);
      if(xr) s += w2 * bf2f(pl[p-127]);
    }
    if(y < 127){
      s += w7 * bf2f(pl[p+128]);
      if(xl) s += w6 * bf2f(pl[p+127]);
      if(xr) s += w8 * bf2f(pl[p+129]);
    }
    unsigned short ob = f2bf(s);
    op[p] = ob;
    float sv = bf2f(ob);            // norms from the *stored* bf16 -> consistent with gram inputs
    ssq += sv*sv;
  }
  if(c < 384){                       // q or k channel
    #pragma unroll
    for(int off=32; off; off>>=1) ssq += __shfl_down(ssq, off, 64);
    if((t & 63) == 0) atomicAdd(&norm2[b*384 + c], ssq);
  }
}

// ---------------- v transpose: dwb v-part [192][HW] -> vT [HW][192] bf16 ----------------
__global__ __launch_bounds__(256) void k_transpose_v(const unsigned short* __restrict__ dwb,
                                                     unsigned short* __restrict__ vT){
  __shared__ unsigned short tile[64][65];
  const int nt = blockIdx.x & 255;
  const int cg = (blockIdx.x >> 8) % 3;
  const int b  = blockIdx.x / 768;
  const unsigned short* ip = dwb + ((size_t)(b*C3_ + 384 + cg*64))*HW_ + nt*64;
  #pragma unroll
  for(int i=0;i<16;i++){
    int idx = threadIdx.x + (i<<8);
    int r = idx >> 6, cc = idx & 63;        // r = ch-local, cc = n-local
    tile[r][cc] = ip[(size_t)r*HW_ + cc];
  }
  __syncthreads();
  unsigned short* op = vT + ((size_t)(b*HW_ + nt*64))*C_ + cg*64;
  #pragma unroll
  for(int i=0;i<16;i++){
    int idx = threadIdx.x + (i<<8);
    int r = idx >> 6, cc = idx & 63;        // r = n-local, cc = ch-local
    op[(size_t)r*C_ + cc] = tile[cc][r];
  }
}

// ---------------- gram: G[b,h][c][d] += sum_n q[c][n]*k[d][n] ----------------
__global__ __launch_bounds__(256) void k_gram(const unsigned short* __restrict__ dwb,
                                              float* __restrict__ G){
  __shared__ alignas(16) unsigned char smem[50688];
  unsigned short (*qs)[264] = (unsigned short(*)[264])smem;
  unsigned short (*ks)[264] = (unsigned short(*)[264])(smem + 48*264*2);
  float* red = (float*)smem;                 // reused after final barrier (36864 B <= 50688)
  const int sl = blockIdx.x & 15;
  const int h  = (blockIdx.x >> 4) & 3;
  const int b  = blockIdx.x >> 6;
  const int n0 = sl * 1024;
  const unsigned short* qp = dwb + ((size_t)(b*C3_ +       h*CHD_))*HW_;
  const unsigned short* kp = dwb + ((size_t)(b*C3_ + 192 + h*CHD_))*HW_;
  const int t = threadIdx.x, lane = t & 63, wv = t >> 6;
  const int g = lane >> 4, rr = lane & 15;
  f4 acc[3][3];
  #pragma unroll
  for(int i=0;i<3;i++)
    #pragma unroll
    for(int j=0;j<3;j++) acc[i][j] = f4{0,0,0,0};
  for(int chunk=0; chunk<4; chunk++){
    const int nb = n0 + chunk*256;
    if(chunk) __syncthreads();
    #pragma unroll
    for(int i=0;i<6;i++){
      int idx = t + (i<<8);
      int r = idx >> 5, o8 = idx & 31;
      *(bfrag*)&qs[r][o8*8] = *(const bfrag*)(qp + (size_t)r*HW_ + nb + o8*8);
    }
    #pragma unroll
    for(int i=0;i<6;i++){
      int idx = t + (i<<8);
      int r = idx >> 5, o8 = idx & 31;
      *(bfrag*)&ks[r][o8*8] = *(const bfrag*)(kp + (size_t)r*HW_ + nb + o8*8);
    }
    __syncthreads();
    #pragma unroll
    for(int s=0; s<2; s++){
      const int kloc = wv*64 + s*32 + g*8;
      bfrag a0 = *(const bfrag*)&qs[ 0 + rr][kloc];
      bfrag a1 = *(const bfrag*)&qs[16 + rr][kloc];
      bfrag a2 = *(const bfrag*)&qs[32 + rr][kloc];
      bfrag b0 = *(const bfrag*)&ks[ 0 + rr][kloc];
      bfrag b1 = *(const bfrag*)&ks[16 + rr][kloc];
      bfrag b2 = *(const bfrag*)&ks[32 + rr][kloc];
      acc[0][0] = __builtin_amdgcn_mfma_f32_16x16x32_bf16(a0, b0, acc[0][0], 0,0,0);
      acc[0][1] = __builtin_amdgcn_mfma_f32_16x16x32_bf16(a0, b1, acc[0][1], 0,0,0);
      acc[0][2] = __builtin_amdgcn_mfma_f32_16x16x32_bf16(a0, b2, acc[0][2], 0,0,0);
      acc[1][0] = __builtin_amdgcn_mfma_f32_16x16x32_bf16(a1, b0, acc[1][0], 0,0,0);
      acc[1][1] = __builtin_amdgcn_mfma_f32_16x16x32_bf16(a1, b1, acc[1][1], 0,0,0);
      acc[1][2] = __builtin_amdgcn_mfma_f32_16x16x32_bf16(a1, b2, acc[1][2], 0,0,0);
      acc[2][0] = __builtin_amdgcn_mfma_f32_16x16x32_bf16(a2, b0, acc[2][0], 0,0,0);
      acc[2][1] = __builtin_amdgcn_mfma_f32_16x16x32_bf16(a2, b1, acc[2][1], 0,0,0);
      acc[2][2] = __builtin_amdgcn_mfma_f32_16x16x32_bf16(a2, b2, acc[2][2], 0,0,0);
    }
  }
  __syncthreads();
  #pragma unroll
  for(int i=0;i<3;i++)
    #pragma unroll
    for(int j=0;j<3;j++)
      #pragma unroll
      for(int r=0;r<4;r++)
        red[wv*2304 + (i*16 + g*4 + r)*48 + j*16 + rr] = acc[i][j][r];
  __syncthreads();
  float* gp = G + (size_t)(b*4 + h)*2304;
  #pragma unroll
  for(int i=0;i<9;i++){
    int e = t + (i<<8);
    float s = red[e] + red[2304 + e] + red[4608 + e] + red[6912 + e];
    atomicAdd(&gp[e], s);
  }
}

// ---------------- softmax over d with L2-norm scaling + temperature ----------------
__global__ __launch_bounds__(64) void k_softmax(const float* __restrict__ G,
                                                const float* __restrict__ norm2,
                                                const float* __restrict__ temp,
                                                float* __restrict__ attnb){
  const int h = blockIdx.x & 3, b = blockIdx.x >> 2;
  const int t = threadIdx.x;
  if(t < 48){
    const float* gr = G + (size_t)(b*4 + h)*2304 + t*48;
    float qn = sqrtf(norm2[b*384 + h*CHD_ + t]);
    float invq = temp[h] / fmaxf(qn, 1e-12f);
    float l[48];
    float mx = -1e30f;
    #pragma unroll
    for(int d=0; d<48; d++){
      float kn = sqrtf(norm2[b*384 + 192 + h*CHD_ + d]);
      l[d] = gr[d] * invq / fmaxf(kn, 1e-12f);
      mx = fmaxf(mx, l[d]);
    }
    float sum = 0.f;
    #pragma unroll
    for(int d=0; d<48; d++){ float e = expf(l[d] - mx); l[d] = e; sum += e; }
    float inv = 1.f / sum;
    float* ar = attnb + (size_t)(b*4 + h)*2304 + t*48;
    #pragma unroll
    for(int d=0; d<48; d++) ar[d] = l[d] * inv;
  }
}

// ---------------- fold: M_b[oc][h*48+d] = sum_c projw[oc][h*48+c] * attn[h][c][d] ----------------
__global__ __launch_bounds__(256) void k_fold(const float* __restrict__ attnb,
                                              const float* __restrict__ projw,
                                              unsigned short* __restrict__ Mb){
  const int og = blockIdx.x & 7, b = blockIdx.x >> 3;
  const int t = threadIdx.x;
  __shared__ float at[4*48*48];
  #pragma unroll
  for(int i=0;i<36;i++){
    int e = t + (i<<8);
    at[e] = attnb[(size_t)b*9216 + e];
  }
  __syncthreads();
  #pragma unroll
  for(int i=0;i<18;i++){
    int e = t + (i<<8);                 // 0..4607
    int oc = og*24 + e/192, cgc = e%192;
    int h = cgc/48, d = cgc%48;
    const float* wr = projw + oc*192 + h*48;
    const float* ac = &at[h*2304 + d];
    float s = 0.f;
    #pragma unroll
    for(int cc=0; cc<48; cc++) s += wr[cc] * ac[cc*48];
    Mb[((size_t)b*192 + oc)*192 + cgc] = f2bf(s);
  }
}

// ---------------- out GEMM: out[b][oc][n] = sum_k M_b[oc][k] * vT[n][k] ----------------
__global__ __launch_bounds__(256) void k_out_gemm(const unsigned short* __restrict__ vT,
                                                  const unsigned short* __restrict__ Mb,
                                                  float* __restrict__ out){
  __shared__ alignas(16) unsigned short vs[128][200];
  __shared__ alignas(16) unsigned short ms[64][200];
  const int nt = blockIdx.x & 127, b = blockIdx.x >> 7;
  const int t = threadIdx.x, lane = t & 63, wv = t >> 6;
  const int g = lane >> 4, rr = lane & 15;
  const unsigned short* vp = vT + ((size_t)(b*HW_ + nt*128))*C_;
  #pragma unroll
  for(int i=0;i<12;i++){
    int idx = t + (i<<8);
    int r = idx/24, c8 = idx%24;
    *(bfrag*)&vs[r][c8*8] = *(const bfrag*)(vp + (size_t)r*C_ + c8*8);
  }
  const unsigned short* mp = Mb + (size_t)b*192*192;
  float* op = out + (size_t)b*C_*HW_ + nt*128;
  for(int ct=0; ct<3; ct++){
    if(ct) __syncthreads();
    #pragma unroll
    for(int i=0;i<6;i++){
      int idx = t + (i<<8);
      int r = idx/24, c8 = idx%24;
      *(bfrag*)&ms[r][c8*8] = *(const bfrag*)(mp + (size_t)(ct*64 + r)*192 + c8*8);
    }
    __syncthreads();
    f4 acc[8];
    #pragma unroll
    for(int j=0;j<8;j++) acc[j] = f4{0,0,0,0};
    #pragma unroll
    for(int kk=0; kk<6; kk++){
      const int ko = kk*32 + g*8;
      bfrag a = *(const bfrag*)&ms[wv*16 + rr][ko];
      #pragma unroll
      for(int j=0;j<8;j++){
        bfrag bb = *(const bfrag*)&vs[j*16 + rr][ko];
        acc[j] = __builtin_amdgcn_mfma_f32_16x16x32_bf16(a, bb, acc[j], 0,0,0);
      }
    }
    #pragma unroll
    for(int j=0;j<8;j++)
      #pragma unroll
      for(int r=0;r<4;r++){
        int oc = ct*64 + wv*16 + g*4 + r;
        op[(size_t)oc*HW_ + j*16 + rr] = acc[j][r];
      }
  }
}

// ---------------- workspace layout (bytes) ----------------
#define OFF_XBT   0ULL                     // 50331648  (aliased by vT after qkv GEMM)
#define OFF_WB    50331648ULL              // 221184
#define OFF_QKVB  50552832ULL              // 150994944
#define OFF_DWB   201547776ULL             // 150994944
#define OFF_G     352542720ULL             // 294912
#define OFF_N2    352837632ULL             // 12288
#define OFF_ATTN  352849920ULL             // 294912
#define OFF_MB    353144832ULL             // 589824  -> total 353734656

extern "C" void kernel_launch(void* const* d_in, const int* in_sizes, int n_in,
                              void* d_out, int out_size, void* d_ws, size_t ws_size,
                              hipStream_t stream) {
  const float* x     = (const float*)d_in[0];
  const float* qkvw  = (const float*)d_in[1];
  const float* dww   = (const float*)d_in[2];
  const float* projw = (const float*)d_in[3];
  const float* temp  = (const float*)d_in[4];
  float* out = (float*)d_out;
  char* ws = (char*)d_ws;

  unsigned short* xbT  = (unsigned short*)(ws + OFF_XBT);
  unsigned short* vTT  = (unsigned short*)(ws + OFF_XBT);   // alias: xbT dead before vT written
  unsigned short* wb   = (unsigned short*)(ws + OFF_WB);
  unsigned short* qkvb = (unsigned short*)(ws + OFF_QKVB);
  unsigned short* dwb  = (unsigned short*)(ws + OFF_DWB);
  float* G     = (float*)(ws + OFF_G);
  float* n2    = (float*)(ws + OFF_N2);
  float* attnb = (float*)(ws + OFF_ATTN);
  unsigned short* Mb = (unsigned short*)(ws + OFF_MB);

  k_init<<<300, 256, 0, stream>>>(G, 76800);                 // G + n2 contiguous
  k_conv_w<<<128, 256, 0, stream>>>(qkvw, wb, C3_*C_);
  k_transpose_x<<<6144, 256, 0, stream>>>(x, xbT);
  k_qkv_gemm<<<2048, 256, 0, stream>>>(xbT, wb, qkvb);
  k_dw<<<4608, 256, 0, stream>>>(qkvb, dww, dwb, n2);
  k_transpose_v<<<6144, 256, 0, stream>>>(dwb, vTT);
  k_gram<<<512, 256, 0, stream>>>(dwb, G);
  k_softmax<<<32, 64, 0, stream>>>(G, n2, temp, attnb);
  k_fold<<<64, 256, 0, stream>>>(attnb, projw, Mb);
  k_out_gemm<<<1024, 256, 0, stream>>>(vTT, Mb, out);
}

// Round 2
// 422.749 us; speedup vs baseline: 1.1156x; 1.1156x over previous
//
#include <hip/hip_runtime.h>

// Pipeline for XCA channel attention (B=8, C=192, HW=128x128, heads=4, ch=48):
//  k_init        : zero G + norm2 accumulators
//  k_conv_w      : qkv_w fp32 -> bf16 [576][192]
//  k_transpose_x : x [b][192][HW] fp32 -> xbT [b][HW][192] bf16 (NHWC, K-contig for MFMA B-frags)
//  k_qkv_gemm    : qkv[b] = Wqkv(576x192) @ x[b](192xHW), bf16 MFMA, out bf16 [b][576][HW]
//  k_dw          : depthwise 3x3 pad1, register-resident rows + shfl halo; fused q/k sum-sq
//  k_transpose_v : v channels -> vT [b][HW][192] bf16
//  k_gram        : G[b,h] = q @ k^T (48x48, K=HW), K-split across 16 blocks, MFMA + atomicAdd
//  k_softmax     : attn = softmax(G/(|q||k|) * temperature)
//  k_fold        : M_b = Wproj @ blockdiag(attn)  (192x192 per batch, fp32 -> bf16)
//  k_out_gemm    : out[b] = M_b @ v[b]  (fuses attn@v and proj conv), fp32 out

#define B_    8
#define C_    192
#define C3_   576
#define IMG_  128
#define HW_   16384
#define HEADS_ 4
#define CHD_  48

typedef short bfrag __attribute__((ext_vector_type(8)));
typedef float f4 __attribute__((ext_vector_type(4)));

__device__ __forceinline__ unsigned short f2bf(float f){
  unsigned int u = __builtin_bit_cast(unsigned int, f);
  u += 0x7fffu + ((u >> 16) & 1u);          // round-to-nearest-even
  return (unsigned short)(u >> 16);
}
__device__ __forceinline__ float bf2f(unsigned short h){
  unsigned int u = ((unsigned int)h) << 16;
  return __builtin_bit_cast(float, u);
}

// ---------------- init: zero G (8*4*48*48) + norm2 (8*384) ----------------
__global__ __launch_bounds__(256) void k_init(float* __restrict__ p, int n){
  int i = blockIdx.x*256 + threadIdx.x;
  if(i < n) p[i] = 0.f;
}

// ---------------- W conversion ----------------
__global__ __launch_bounds__(256) void k_conv_w(const float* __restrict__ w,
                                                unsigned short* __restrict__ o, int n){
  for(int i = blockIdx.x*256 + threadIdx.x; i < n; i += gridDim.x*256)
    o[i] = f2bf(w[i]);
}

// ---------------- x transpose: [b][192][HW] f32 -> [b][HW][192] bf16 ----------------
__global__ __launch_bounds__(256) void k_transpose_x(const float* __restrict__ x,
                                                     unsigned short* __restrict__ xbT){
  __shared__ float tile[64][65];
  const int nt = blockIdx.x & 255;
  const int cg = (blockIdx.x >> 8) % 3;
  const int b  = blockIdx.x / 768;
  const float* xp = x + ((size_t)(b*C_ + cg*64))*HW_ + nt*64;
  #pragma unroll
  for(int i=0;i<16;i++){
    int idx = threadIdx.x + (i<<8);
    int r = idx >> 6, cc = idx & 63;        // r = ch-local, cc = n-local
    tile[r][cc] = xp[(size_t)r*HW_ + cc];
  }
  __syncthreads();
  unsigned short* op = xbT + ((size_t)(b*HW_ + nt*64))*C_ + cg*64;
  #pragma unroll
  for(int i=0;i<16;i++){
    int idx = threadIdx.x + (i<<8);
    int r = idx >> 6, cc = idx & 63;        // r = n-local, cc = ch-local
    op[(size_t)r*C_ + cc] = f2bf(tile[cc][r]);
  }
}

// ---------------- qkv GEMM: D[oc][n] = W[oc][k] * xT[n][k] ----------------
__global__ __launch_bounds__(256) void k_qkv_gemm(const unsigned short* __restrict__ xbT,
                                                  const unsigned short* __restrict__ wb,
                                                  unsigned short* __restrict__ qkvb){
  __shared__ alignas(16) unsigned short xs[64][200];   // [pixel][k], pad->200 (stride=4 banks mod 32)
  __shared__ alignas(16) unsigned short wsl[64][200];  // [oc][k]
  const int nt = blockIdx.x & 255, b = blockIdx.x >> 8;
  const int t = threadIdx.x, lane = t & 63, wv = t >> 6;
  const unsigned short* xp = xbT + ((size_t)(b*HW_ + nt*64))*C_;
  #pragma unroll
  for(int i=0;i<6;i++){
    int idx = t + (i<<8);
    int r = idx/24, c8 = idx%24;
    *(bfrag*)&xs[r][c8*8] = *(const bfrag*)(xp + (size_t)r*C_ + c8*8);
  }
  const int g = lane >> 4, rr = lane & 15;
  for(int ct=0; ct<9; ct++){
    if(ct) __syncthreads();
    const unsigned short* wp = wb + (size_t)(ct*64)*C_;
    #pragma unroll
    for(int i=0;i<6;i++){
      int idx = t + (i<<8);
      int r = idx/24, c8 = idx%24;
      *(bfrag*)&wsl[r][c8*8] = *(const bfrag*)(wp + (size_t)r*C_ + c8*8);
    }
    __syncthreads();
    f4 acc0={0,0,0,0}, acc1={0,0,0,0}, acc2={0,0,0,0}, acc3={0,0,0,0};
    #pragma unroll
    for(int kk=0; kk<6; kk++){
      const int ko = kk*32 + g*8;
      bfrag a  = *(const bfrag*)&wsl[wv*16 + rr][ko];
      bfrag b0 = *(const bfrag*)&xs[ 0 + rr][ko];
      bfrag b1 = *(const bfrag*)&xs[16 + rr][ko];
      bfrag b2 = *(const bfrag*)&xs[32 + rr][ko];
      bfrag b3 = *(const bfrag*)&xs[48 + rr][ko];
      acc0 = __builtin_amdgcn_mfma_f32_16x16x32_bf16(a, b0, acc0, 0,0,0);
      acc1 = __builtin_amdgcn_mfma_f32_16x16x32_bf16(a, b1, acc1, 0,0,0);
      acc2 = __builtin_amdgcn_mfma_f32_16x16x32_bf16(a, b2, acc2, 0,0,0);
      acc3 = __builtin_amdgcn_mfma_f32_16x16x32_bf16(a, b3, acc3, 0,0,0);
    }
    // D: col = lane&15 (n), row = (lane>>4)*4 + reg (oc)
    unsigned short* op = qkvb + ((size_t)(b*C3_ + ct*64 + wv*16 + g*4))*HW_ + nt*64 + rr;
    #pragma unroll
    for(int r=0;r<4;r++){
      op[(size_t)r*HW_ +  0] = f2bf(acc0[r]);
      op[(size_t)r*HW_ + 16] = f2bf(acc1[r]);
      op[(size_t)r*HW_ + 32] = f2bf(acc2[r]);
      op[(size_t)r*HW_ + 48] = f2bf(acc3[r]);
    }
  }
}

// ---------------- depthwise 3x3, pad 1; register rows + shfl halo; fused q/k ssq ----------------
// block: 256 thr = 4 waves; wave = 4 rows x 128 px (16 lanes/row, 8 px/thread)
// grid: 8 row-tiles x 576 ch x 8 batch = 36864 blocks
__global__ __launch_bounds__(256) void k_dw(const unsigned short* __restrict__ qkvb,
                                            const float* __restrict__ dww,
                                            unsigned short* __restrict__ dwb,
                                            float* __restrict__ norm2){
  const int rt = blockIdx.x & 7;
  const int c  = (blockIdx.x >> 3) % C3_;
  const int b  = blockIdx.x / (8*C3_);
  const int t = threadIdx.x, lane = t & 63, wv = t >> 6;
  const int x0 = (lane & 15) << 3;
  const int row = rt*16 + wv*4 + (lane >> 4);
  const unsigned short* ip = qkvb + ((size_t)(b*C3_ + c))*HW_;
  const float w0=dww[c*9+0], w1=dww[c*9+1], w2=dww[c*9+2],
              w3=dww[c*9+3], w4=dww[c*9+4], w5=dww[c*9+5],
              w6=dww[c*9+6], w7=dww[c*9+7], w8=dww[c*9+8];

  float top[8], mid[8], bot[8];
  {
    // own row always valid
    bfrag v = *(const bfrag*)(ip + (size_t)row*IMG_ + x0);
    #pragma unroll
    for(int j=0;j<8;j++) mid[j] = bf2f((unsigned short)v[j]);
  }
  if(row > 0){
    bfrag v = *(const bfrag*)(ip + (size_t)(row-1)*IMG_ + x0);
    #pragma unroll
    for(int j=0;j<8;j++) top[j] = bf2f((unsigned short)v[j]);
  } else {
    #pragma unroll
    for(int j=0;j<8;j++) top[j] = 0.f;
  }
  if(row < IMG_-1){
    bfrag v = *(const bfrag*)(ip + (size_t)(row+1)*IMG_ + x0);
    #pragma unroll
    for(int j=0;j<8;j++) bot[j] = bf2f((unsigned short)v[j]);
  } else {
    #pragma unroll
    for(int j=0;j<8;j++) bot[j] = 0.f;
  }

  float acc[8];
  #pragma unroll
  for(int j=0;j<8;j++) acc[j] = 0.f;

  const int lm = (lane + 63) & 63, lp = (lane + 1) & 63;
  const bool atL = (x0 == 0), atR = (x0 == 120);
  {
    float lft = __shfl(top[7], lm); if(atL) lft = 0.f;
    float rgt = __shfl(top[0], lp); if(atR) rgt = 0.f;
    acc[0] += w0*lft + w1*top[0] + w2*top[1];
    #pragma unroll
    for(int j=1;j<7;j++) acc[j] += w0*top[j-1] + w1*top[j] + w2*top[j+1];
    acc[7] += w0*top[6] + w1*top[7] + w2*rgt;
  }
  {
    float lft = __shfl(mid[7], lm); if(atL) lft = 0.f;
    float rgt = __shfl(mid[0], lp); if(atR) rgt = 0.f;
    acc[0] += w3*lft + w4*mid[0] + w5*mid[1];
    #pragma unroll
    for(int j=1;j<7;j++) acc[j] += w3*mid[j-1] + w4*mid[j] + w5*mid[j+1];
    acc[7] += w3*mid[6] + w4*mid[7] + w5*rgt;
  }
  {
    float lft = __shfl(bot[7], lm); if(atL) lft = 0.f;
    float rgt = __shfl(bot[0], lp); if(atR) rgt = 0.f;
    acc[0] += w6*lft + w7*bot[0] + w8*bot[1];
    #pragma unroll
    for(int j=1;j<7;j++) acc[j] += w6*bot[j-1] + w7*bot[j] + w8*bot[j+1];
    acc[7] += w6*bot[6] + w7*bot[7] + w8*rgt;
  }

  bfrag ov;
  float ssq = 0.f;
  #pragma unroll
  for(int j=0;j<8;j++){
    unsigned short ob = f2bf(acc[j]);
    ov[j] = (short)ob;
    float sv = bf2f(ob);            // norms from stored bf16 -> consistent with gram inputs
    ssq += sv*sv;
  }
  *(bfrag*)(dwb + ((size_t)(b*C3_ + c))*HW_ + (size_t)row*IMG_ + x0) = ov;

  if(c < 384){
    #pragma unroll
    for(int off=32; off; off>>=1) ssq += __shfl_down(ssq, off, 64);
    if(lane == 0) atomicAdd(&norm2[b*384 + c], ssq);
  }
}

// ---------------- v transpose: dwb v-part [192][HW] -> vT [HW][192] bf16 ----------------
__global__ __launch_bounds__(256) void k_transpose_v(const unsigned short* __restrict__ dwb,
                                                     unsigned short* __restrict__ vT){
  __shared__ unsigned short tile[64][65];
  const int nt = blockIdx.x & 255;
  const int cg = (blockIdx.x >> 8) % 3;
  const int b  = blockIdx.x / 768;
  const unsigned short* ip = dwb + ((size_t)(b*C3_ + 384 + cg*64))*HW_ + nt*64;
  #pragma unroll
  for(int i=0;i<16;i++){
    int idx = threadIdx.x + (i<<8);
    int r = idx >> 6, cc = idx & 63;        // r = ch-local, cc = n-local
    tile[r][cc] = ip[(size_t)r*HW_ + cc];
  }
  __syncthreads();
  unsigned short* op = vT + ((size_t)(b*HW_ + nt*64))*C_ + cg*64;
  #pragma unroll
  for(int i=0;i<16;i++){
    int idx = threadIdx.x + (i<<8);
    int r = idx >> 6, cc = idx & 63;        // r = n-local, cc = ch-local
    op[(size_t)r*C_ + cc] = tile[cc][r];
  }
}

// ---------------- gram: G[b,h][c][d] += sum_n q[c][n]*k[d][n] ----------------
__global__ __launch_bounds__(256) void k_gram(const unsigned short* __restrict__ dwb,
                                              float* __restrict__ G){
  __shared__ alignas(16) unsigned char smem[50688];
  unsigned short (*qs)[264] = (unsigned short(*)[264])smem;
  unsigned short (*ks)[264] = (unsigned short(*)[264])(smem + 48*264*2);
  float* red = (float*)smem;                 // reused after final barrier (36864 B <= 50688)
  const int sl = blockIdx.x & 15;
  const int h  = (blockIdx.x >> 4) & 3;
  const int b  = blockIdx.x >> 6;
  const int n0 = sl * 1024;
  const unsigned short* qp = dwb + ((size_t)(b*C3_ +       h*CHD_))*HW_;
  const unsigned short* kp = dwb + ((size_t)(b*C3_ + 192 + h*CHD_))*HW_;
  const int t = threadIdx.x, lane = t & 63, wv = t >> 6;
  const int g = lane >> 4, rr = lane & 15;
  f4 acc[3][3];
  #pragma unroll
  for(int i=0;i<3;i++)
    #pragma unroll
    for(int j=0;j<3;j++) acc[i][j] = f4{0,0,0,0};
  for(int chunk=0; chunk<4; chunk++){
    const int nb = n0 + chunk*256;
    if(chunk) __syncthreads();
    #pragma unroll
    for(int i=0;i<6;i++){
      int idx = t + (i<<8);
      int r = idx >> 5, o8 = idx & 31;
      *(bfrag*)&qs[r][o8*8] = *(const bfrag*)(qp + (size_t)r*HW_ + nb + o8*8);
    }
    #pragma unroll
    for(int i=0;i<6;i++){
      int idx = t + (i<<8);
      int r = idx >> 5, o8 = idx & 31;
      *(bfrag*)&ks[r][o8*8] = *(const bfrag*)(kp + (size_t)r*HW_ + nb + o8*8);
    }
    __syncthreads();
    #pragma unroll
    for(int s=0; s<2; s++){
      const int kloc = wv*64 + s*32 + g*8;
      bfrag a0 = *(const bfrag*)&qs[ 0 + rr][kloc];
      bfrag a1 = *(const bfrag*)&qs[16 + rr][kloc];
      bfrag a2 = *(const bfrag*)&qs[32 + rr][kloc];
      bfrag b0 = *(const bfrag*)&ks[ 0 + rr][kloc];
      bfrag b1 = *(const bfrag*)&ks[16 + rr][kloc];
      bfrag b2 = *(const bfrag*)&ks[32 + rr][kloc];
      acc[0][0] = __builtin_amdgcn_mfma_f32_16x16x32_bf16(a0, b0, acc[0][0], 0,0,0);
      acc[0][1] = __builtin_amdgcn_mfma_f32_16x16x32_bf16(a0, b1, acc[0][1], 0,0,0);
      acc[0][2] = __builtin_amdgcn_mfma_f32_16x16x32_bf16(a0, b2, acc[0][2], 0,0,0);
      acc[1][0] = __builtin_amdgcn_mfma_f32_16x16x32_bf16(a1, b0, acc[1][0], 0,0,0);
      acc[1][1] = __builtin_amdgcn_mfma_f32_16x16x32_bf16(a1, b1, acc[1][1], 0,0,0);
      acc[1][2] = __builtin_amdgcn_mfma_f32_16x16x32_bf16(a1, b2, acc[1][2], 0,0,0);
      acc[2][0] = __builtin_amdgcn_mfma_f32_16x16x32_bf16(a2, b0, acc[2][0], 0,0,0);
      acc[2][1] = __builtin_amdgcn_mfma_f32_16x16x32_bf16(a2, b1, acc[2][1], 0,0,0);
      acc[2][2] = __builtin_amdgcn_mfma_f32_16x16x32_bf16(a2, b2, acc[2][2], 0,0,0);
    }
  }
  __syncthreads();
  #pragma unroll
  for(int i=0;i<3;i++)
    #pragma unroll
    for(int j=0;j<3;j++)
      #pragma unroll
      for(int r=0;r<4;r++)
        red[wv*2304 + (i*16 + g*4 + r)*48 + j*16 + rr] = acc[i][j][r];
  __syncthreads();
  float* gp = G + (size_t)(b*4 + h)*2304;
  #pragma unroll
  for(int i=0;i<9;i++){
    int e = t + (i<<8);
    float s = red[e] + red[2304 + e] + red[4608 + e] + red[6912 + e];
    atomicAdd(&gp[e], s);
  }
}

// ---------------- softmax over d with L2-norm scaling + temperature ----------------
__global__ __launch_bounds__(64) void k_softmax(const float* __restrict__ G,
                                                const float* __restrict__ norm2,
                                                const float* __restrict__ temp,
                                                float* __restrict__ attnb){
  const int h = blockIdx.x & 3, b = blockIdx.x >> 2;
  const int t = threadIdx.x;
  if(t < 48){
    const float* gr = G + (size_t)(b*4 + h)*2304 + t*48;
    float qn = sqrtf(norm2[b*384 + h*CHD_ + t]);
    float invq = temp[h] / fmaxf(qn, 1e-12f);
    float l[48];
    float mx = -1e30f;
    #pragma unroll
    for(int d=0; d<48; d++){
      float kn = sqrtf(norm2[b*384 + 192 + h*CHD_ + d]);
      l[d] = gr[d] * invq / fmaxf(kn, 1e-12f);
      mx = fmaxf(mx, l[d]);
    }
    float sum = 0.f;
    #pragma unroll
    for(int d=0; d<48; d++){ float e = expf(l[d] - mx); l[d] = e; sum += e; }
    float inv = 1.f / sum;
    float* ar = attnb + (size_t)(b*4 + h)*2304 + t*48;
    #pragma unroll
    for(int d=0; d<48; d++) ar[d] = l[d] * inv;
  }
}

// ---------------- fold: M_b[oc][h*48+d] = sum_c projw[oc][h*48+c] * attn[h][c][d] ----------------
__global__ __launch_bounds__(256) void k_fold(const float* __restrict__ attnb,
                                              const float* __restrict__ projw,
                                              unsigned short* __restrict__ Mb){
  const int og = blockIdx.x & 7, b = blockIdx.x >> 3;
  const int t = threadIdx.x;
  __shared__ float at[4*48*48];
  #pragma unroll
  for(int i=0;i<36;i++){
    int e = t + (i<<8);
    at[e] = attnb[(size_t)b*9216 + e];
  }
  __syncthreads();
  #pragma unroll
  for(int i=0;i<18;i++){
    int e = t + (i<<8);                 // 0..4607
    int oc = og*24 + e/192, cgc = e%192;
    int h = cgc/48, d = cgc%48;
    const float* wr = projw + oc*192 + h*48;
    const float* ac = &at[h*2304 + d];
    float s = 0.f;
    #pragma unroll
    for(int cc=0; cc<48; cc++) s += wr[cc] * ac[cc*48];
    Mb[((size_t)b*192 + oc)*192 + cgc] = f2bf(s);
  }
}

// ---------------- out GEMM: out[b][oc][n] = sum_k M_b[oc][k] * vT[n][k] ----------------
__global__ __launch_bounds__(256) void k_out_gemm(const unsigned short* __restrict__ vT,
                                                  const unsigned short* __restrict__ Mb,
                                                  float* __restrict__ out){
  __shared__ alignas(16) unsigned short vs[128][200];
  __shared__ alignas(16) unsigned short ms[64][200];
  const int nt = blockIdx.x & 127, b = blockIdx.x >> 7;
  const int t = threadIdx.x, lane = t & 63, wv = t >> 6;
  const int g = lane >> 4, rr = lane & 15;
  const unsigned short* vp = vT + ((size_t)(b*HW_ + nt*128))*C_;
  #pragma unroll
  for(int i=0;i<12;i++){
    int idx = t + (i<<8);
    int r = idx/24, c8 = idx%24;
    *(bfrag*)&vs[r][c8*8] = *(const bfrag*)(vp + (size_t)r*C_ + c8*8);
  }
  const unsigned short* mp = Mb + (size_t)b*192*192;
  float* op = out + (size_t)b*C_*HW_ + nt*128;
  for(int ct=0; ct<3; ct++){
    if(ct) __syncthreads();
    #pragma unroll
    for(int i=0;i<6;i++){
      int idx = t + (i<<8);
      int r = idx/24, c8 = idx%24;
      *(bfrag*)&ms[r][c8*8] = *(const bfrag*)(mp + (size_t)(ct*64 + r)*192 + c8*8);
    }
    __syncthreads();
    f4 acc[8];
    #pragma unroll
    for(int j=0;j<8;j++) acc[j] = f4{0,0,0,0};
    #pragma unroll
    for(int kk=0; kk<6; kk++){
      const int ko = kk*32 + g*8;
      bfrag a = *(const bfrag*)&ms[wv*16 + rr][ko];
      #pragma unroll
      for(int j=0;j<8;j++){
        bfrag bb = *(const bfrag*)&vs[j*16 + rr][ko];
        acc[j] = __builtin_amdgcn_mfma_f32_16x16x32_bf16(a, bb, acc[j], 0,0,0);
      }
    }
    #pragma unroll
    for(int j=0;j<8;j++)
      #pragma unroll
      for(int r=0;r<4;r++){
        int oc = ct*64 + wv*16 + g*4 + r;
        op[(size_t)oc*HW_ + j*16 + rr] = acc[j][r];
      }
  }
}

// ---------------- workspace layout (bytes) ----------------
#define OFF_XBT   0ULL                     // 50331648  (aliased by vT after qkv GEMM)
#define OFF_WB    50331648ULL              // 221184
#define OFF_QKVB  50552832ULL              // 150994944
#define OFF_DWB   201547776ULL             // 150994944
#define OFF_G     352542720ULL             // 294912
#define OFF_N2    352837632ULL             // 12288
#define OFF_ATTN  352849920ULL             // 294912
#define OFF_MB    353144832ULL             // 589824  -> total 353734656

extern "C" void kernel_launch(void* const* d_in, const int* in_sizes, int n_in,
                              void* d_out, int out_size, void* d_ws, size_t ws_size,
                              hipStream_t stream) {
  const float* x     = (const float*)d_in[0];
  const float* qkvw  = (const float*)d_in[1];
  const float* dww   = (const float*)d_in[2];
  const float* projw = (const float*)d_in[3];
  const float* temp  = (const float*)d_in[4];
  float* out = (float*)d_out;
  char* ws = (char*)d_ws;

  unsigned short* xbT  = (unsigned short*)(ws + OFF_XBT);
  unsigned short* vTT  = (unsigned short*)(ws + OFF_XBT);   // alias: xbT dead before vT written
  unsigned short* wb   = (unsigned short*)(ws + OFF_WB);
  unsigned short* qkvb = (unsigned short*)(ws + OFF_QKVB);
  unsigned short* dwb  = (unsigned short*)(ws + OFF_DWB);
  float* G     = (float*)(ws + OFF_G);
  float* n2    = (float*)(ws + OFF_N2);
  float* attnb = (float*)(ws + OFF_ATTN);
  unsigned short* Mb = (unsigned short*)(ws + OFF_MB);

  k_init<<<300, 256, 0, stream>>>(G, 76800);                 // G + n2 contiguous
  k_conv_w<<<128, 256, 0, stream>>>(qkvw, wb, C3_*C_);
  k_transpose_x<<<6144, 256, 0, stream>>>(x, xbT);
  k_qkv_gemm<<<2048, 256, 0, stream>>>(xbT, wb, qkvb);
  k_dw<<<36864, 256, 0, stream>>>(qkvb, dww, dwb, n2);
  k_transpose_v<<<6144, 256, 0, stream>>>(dwb, vTT);
  k_gram<<<512, 256, 0, stream>>>(dwb, G);
  k_softmax<<<32, 64, 0, stream>>>(G, n2, temp, attnb);
  k_fold<<<64, 256, 0, stream>>>(attnb, projw, Mb);
  k_out_gemm<<<1024, 256, 0, stream>>>(vTT, Mb, out);
}

// Round 3
// 396.782 us; speedup vs baseline: 1.1886x; 1.0654x over previous
//
#include <hip/hip_runtime.h>

// Pipeline for XCA channel attention (B=8, C=192, HW=128x128, heads=4, ch=48):
//  k_init        : zero G + norm2 accumulators
//  k_conv_w      : qkv_w fp32 -> bf16 [576][192]
//  k_transpose_x : x [b][192][HW] fp32 -> xbT [b][HW][192] bf16 (NHWC, K-contig for MFMA B-frags)
//  k_qkv_gemm    : qkv[b] = Wqkv(576x192) @ x[b](192xHW), bf16 MFMA, out bf16 [b][576][HW]
//  k_dw          : depthwise 3x3 pad1, 2 rows/thread in registers + shfl halo; fused q/k sum-sq
//  k_transpose_v : v channels -> vT [b][HW][192] bf16
//  k_gram        : G[b,h] = q @ k^T (48x48, K=HW), K-split across 16 blocks, MFMA + atomicAdd
//  k_softmax     : attn = softmax(G/(|q||k|) * temperature)
//  k_fold        : M_b = Wproj @ blockdiag(attn)  (192x192 per batch, fp32 -> bf16)
//  k_out_gemm    : out[b] = M_b @ v[b]  (fuses attn@v and proj conv), fp32 out

#define B_    8
#define C_    192
#define C3_   576
#define IMG_  128
#define HW_   16384
#define HEADS_ 4
#define CHD_  48

typedef short bfrag __attribute__((ext_vector_type(8)));
typedef float f4 __attribute__((ext_vector_type(4)));

__device__ __forceinline__ unsigned short f2bf(float f){
  unsigned int u = __builtin_bit_cast(unsigned int, f);
  u += 0x7fffu + ((u >> 16) & 1u);          // round-to-nearest-even
  return (unsigned short)(u >> 16);
}
__device__ __forceinline__ float bf2f(unsigned short h){
  unsigned int u = ((unsigned int)h) << 16;
  return __builtin_bit_cast(float, u);
}

// ---------------- init: zero G (8*4*48*48) + norm2 (8*384) ----------------
__global__ __launch_bounds__(256) void k_init(float* __restrict__ p, int n){
  int i = blockIdx.x*256 + threadIdx.x;
  if(i < n) p[i] = 0.f;
}

// ---------------- W conversion ----------------
__global__ __launch_bounds__(256) void k_conv_w(const float* __restrict__ w,
                                                unsigned short* __restrict__ o, int n){
  for(int i = blockIdx.x*256 + threadIdx.x; i < n; i += gridDim.x*256)
    o[i] = f2bf(w[i]);
}

// ---------------- x transpose: [b][192][HW] f32 -> [b][HW][192] bf16 ----------------
__global__ __launch_bounds__(256) void k_transpose_x(const float* __restrict__ x,
                                                     unsigned short* __restrict__ xbT){
  __shared__ float tile[64][65];
  const int nt = blockIdx.x & 255;
  const int cg = (blockIdx.x >> 8) % 3;
  const int b  = blockIdx.x / 768;
  const float* xp = x + ((size_t)(b*C_ + cg*64))*HW_ + nt*64;
  #pragma unroll
  for(int i=0;i<16;i++){
    int idx = threadIdx.x + (i<<8);
    int r = idx >> 6, cc = idx & 63;        // r = ch-local, cc = n-local
    tile[r][cc] = xp[(size_t)r*HW_ + cc];
  }
  __syncthreads();
  unsigned short* op = xbT + ((size_t)(b*HW_ + nt*64))*C_ + cg*64;
  #pragma unroll
  for(int i=0;i<16;i++){
    int idx = threadIdx.x + (i<<8);
    int r = idx >> 6, cc = idx & 63;        // r = n-local, cc = ch-local
    op[(size_t)r*C_ + cc] = f2bf(tile[cc][r]);
  }
}

// ---------------- qkv GEMM: D[oc][n] = W[oc][k] * xT[n][k] ----------------
__global__ __launch_bounds__(256) void k_qkv_gemm(const unsigned short* __restrict__ xbT,
                                                  const unsigned short* __restrict__ wb,
                                                  unsigned short* __restrict__ qkvb){
  __shared__ alignas(16) unsigned short xs[64][200];   // [pixel][k], pad->200 (stride=4 banks mod 32)
  __shared__ alignas(16) unsigned short wsl[64][200];  // [oc][k]
  const int nt = blockIdx.x & 255, b = blockIdx.x >> 8;
  const int t = threadIdx.x, lane = t & 63, wv = t >> 6;
  const unsigned short* xp = xbT + ((size_t)(b*HW_ + nt*64))*C_;
  #pragma unroll
  for(int i=0;i<6;i++){
    int idx = t + (i<<8);
    int r = idx/24, c8 = idx%24;
    *(bfrag*)&xs[r][c8*8] = *(const bfrag*)(xp + (size_t)r*C_ + c8*8);
  }
  const int g = lane >> 4, rr = lane & 15;
  for(int ct=0; ct<9; ct++){
    if(ct) __syncthreads();
    const unsigned short* wp = wb + (size_t)(ct*64)*C_;
    #pragma unroll
    for(int i=0;i<6;i++){
      int idx = t + (i<<8);
      int r = idx/24, c8 = idx%24;
      *(bfrag*)&wsl[r][c8*8] = *(const bfrag*)(wp + (size_t)r*C_ + c8*8);
    }
    __syncthreads();
    f4 acc0={0,0,0,0}, acc1={0,0,0,0}, acc2={0,0,0,0}, acc3={0,0,0,0};
    #pragma unroll
    for(int kk=0; kk<6; kk++){
      const int ko = kk*32 + g*8;
      bfrag a  = *(const bfrag*)&wsl[wv*16 + rr][ko];
      bfrag b0 = *(const bfrag*)&xs[ 0 + rr][ko];
      bfrag b1 = *(const bfrag*)&xs[16 + rr][ko];
      bfrag b2 = *(const bfrag*)&xs[32 + rr][ko];
      bfrag b3 = *(const bfrag*)&xs[48 + rr][ko];
      acc0 = __builtin_amdgcn_mfma_f32_16x16x32_bf16(a, b0, acc0, 0,0,0);
      acc1 = __builtin_amdgcn_mfma_f32_16x16x32_bf16(a, b1, acc1, 0,0,0);
      acc2 = __builtin_amdgcn_mfma_f32_16x16x32_bf16(a, b2, acc2, 0,0,0);
      acc3 = __builtin_amdgcn_mfma_f32_16x16x32_bf16(a, b3, acc3, 0,0,0);
    }
    // D: col = lane&15 (n), row = (lane>>4)*4 + reg (oc)
    unsigned short* op = qkvb + ((size_t)(b*C3_ + ct*64 + wv*16 + g*4))*HW_ + nt*64 + rr;
    #pragma unroll
    for(int r=0;r<4;r++){
      op[(size_t)r*HW_ +  0] = f2bf(acc0[r]);
      op[(size_t)r*HW_ + 16] = f2bf(acc1[r]);
      op[(size_t)r*HW_ + 32] = f2bf(acc2[r]);
      op[(size_t)r*HW_ + 48] = f2bf(acc3[r]);
    }
  }
}

// ---------------- depthwise 3x3, pad 1; 2 rows/thread, register rows + shfl halo ----------------
// block: 256 thr = 4 waves; wave = 4 row-pairs x 128 px (16 lanes/row, 8 px/thread/row)
// block covers 32 rows of one (b,c); grid: 4 row-tiles x 576 ch x 8 batch = 18432 blocks
__global__ __launch_bounds__(256) void k_dw(const unsigned short* __restrict__ qkvb,
                                            const float* __restrict__ dww,
                                            unsigned short* __restrict__ dwb,
                                            float* __restrict__ norm2){
  const int rt = blockIdx.x & 3;
  const int c  = (blockIdx.x >> 2) % C3_;
  const int b  = blockIdx.x / (4*C3_);
  const int t = threadIdx.x, lane = t & 63, wv = t >> 6;
  const int x0 = (lane & 15) << 3;
  const int row0 = rt*32 + wv*8 + (lane >> 4)*2;     // first of 2 output rows (even, <=126)
  const unsigned short* ip = qkvb + ((size_t)(b*C3_ + c))*HW_;
  const float w0=dww[c*9+0], w1=dww[c*9+1], w2=dww[c*9+2],
              w3=dww[c*9+3], w4=dww[c*9+4], w5=dww[c*9+5],
              w6=dww[c*9+6], w7=dww[c*9+7], w8=dww[c*9+8];

  float r0[8], r1[8], r2[8], r3[8];
  if(row0 > 0){
    bfrag v = *(const bfrag*)(ip + (size_t)(row0-1)*IMG_ + x0);
    #pragma unroll
    for(int j=0;j<8;j++) r0[j] = bf2f((unsigned short)v[j]);
  } else {
    #pragma unroll
    for(int j=0;j<8;j++) r0[j] = 0.f;
  }
  {
    bfrag v = *(const bfrag*)(ip + (size_t)row0*IMG_ + x0);
    #pragma unroll
    for(int j=0;j<8;j++) r1[j] = bf2f((unsigned short)v[j]);
  }
  {
    bfrag v = *(const bfrag*)(ip + (size_t)(row0+1)*IMG_ + x0);
    #pragma unroll
    for(int j=0;j<8;j++) r2[j] = bf2f((unsigned short)v[j]);
  }
  if(row0 < 126){
    bfrag v = *(const bfrag*)(ip + (size_t)(row0+2)*IMG_ + x0);
    #pragma unroll
    for(int j=0;j<8;j++) r3[j] = bf2f((unsigned short)v[j]);
  } else {
    #pragma unroll
    for(int j=0;j<8;j++) r3[j] = 0.f;
  }

  const int lm = (lane + 63) & 63, lp = (lane + 1) & 63;
  const bool atL = (x0 == 0), atR = (x0 == 120);
  float l0 = __shfl(r0[7], lm), rgt0 = __shfl(r0[0], lp);
  float l1 = __shfl(r1[7], lm), rgt1 = __shfl(r1[0], lp);
  float l2 = __shfl(r2[7], lm), rgt2 = __shfl(r2[0], lp);
  float l3 = __shfl(r3[7], lm), rgt3 = __shfl(r3[0], lp);
  if(atL){ l0 = 0.f; l1 = 0.f; l2 = 0.f; l3 = 0.f; }
  if(atR){ rgt0 = 0.f; rgt1 = 0.f; rgt2 = 0.f; rgt3 = 0.f; }

  float accA[8], accB[8];
  #pragma unroll
  for(int j=0;j<8;j++){ accA[j] = 0.f; accB[j] = 0.f; }

  // out row0: taps rows r0,r1,r2 ; out row0+1: taps rows r1,r2,r3
  {
    accA[0] += w0*l0 + w1*r0[0] + w2*r0[1];
    #pragma unroll
    for(int j=1;j<7;j++) accA[j] += w0*r0[j-1] + w1*r0[j] + w2*r0[j+1];
    accA[7] += w0*r0[6] + w1*r0[7] + w2*rgt0;
  }
  {
    accA[0] += w3*l1 + w4*r1[0] + w5*r1[1];
    accB[0] += w0*l1 + w1*r1[0] + w2*r1[1];
    #pragma unroll
    for(int j=1;j<7;j++){
      accA[j] += w3*r1[j-1] + w4*r1[j] + w5*r1[j+1];
      accB[j] += w0*r1[j-1] + w1*r1[j] + w2*r1[j+1];
    }
    accA[7] += w3*r1[6] + w4*r1[7] + w5*rgt1;
    accB[7] += w0*r1[6] + w1*r1[7] + w2*rgt1;
  }
  {
    accA[0] += w6*l2 + w7*r2[0] + w8*r2[1];
    accB[0] += w3*l2 + w4*r2[0] + w5*r2[1];
    #pragma unroll
    for(int j=1;j<7;j++){
      accA[j] += w6*r2[j-1] + w7*r2[j] + w8*r2[j+1];
      accB[j] += w3*r2[j-1] + w4*r2[j] + w5*r2[j+1];
    }
    accA[7] += w6*r2[6] + w7*r2[7] + w8*rgt2;
    accB[7] += w3*r2[6] + w4*r2[7] + w5*rgt2;
  }
  {
    accB[0] += w6*l3 + w7*r3[0] + w8*r3[1];
    #pragma unroll
    for(int j=1;j<7;j++) accB[j] += w6*r3[j-1] + w7*r3[j] + w8*r3[j+1];
    accB[7] += w6*r3[6] + w7*r3[7] + w8*rgt3;
  }

  unsigned short* op = dwb + ((size_t)(b*C3_ + c))*HW_ + (size_t)row0*IMG_ + x0;
  bfrag ovA, ovB;
  float ssq = 0.f;
  #pragma unroll
  for(int j=0;j<8;j++){
    unsigned short oa = f2bf(accA[j]);
    unsigned short ob = f2bf(accB[j]);
    ovA[j] = (short)oa; ovB[j] = (short)ob;
    float sa = bf2f(oa), sb = bf2f(ob);   // norms from stored bf16 -> consistent with gram inputs
    ssq += sa*sa + sb*sb;
  }
  *(bfrag*)op = ovA;
  *(bfrag*)(op + IMG_) = ovB;

  if(c < 384){
    #pragma unroll
    for(int off=32; off; off>>=1) ssq += __shfl_down(ssq, off, 64);
    if(lane == 0) atomicAdd(&norm2[b*384 + c], ssq);
  }
}

// ---------------- v transpose: dwb v-part [192][HW] -> vT [HW][192] bf16 ----------------
__global__ __launch_bounds__(256) void k_transpose_v(const unsigned short* __restrict__ dwb,
                                                     unsigned short* __restrict__ vT){
  __shared__ unsigned short tile[64][65];
  const int nt = blockIdx.x & 255;
  const int cg = (blockIdx.x >> 8) % 3;
  const int b  = blockIdx.x / 768;
  const unsigned short* ip = dwb + ((size_t)(b*C3_ + 384 + cg*64))*HW_ + nt*64;
  #pragma unroll
  for(int i=0;i<16;i++){
    int idx = threadIdx.x + (i<<8);
    int r = idx >> 6, cc = idx & 63;        // r = ch-local, cc = n-local
    tile[r][cc] = ip[(size_t)r*HW_ + cc];
  }
  __syncthreads();
  unsigned short* op = vT + ((size_t)(b*HW_ + nt*64))*C_ + cg*64;
  #pragma unroll
  for(int i=0;i<16;i++){
    int idx = threadIdx.x + (i<<8);
    int r = idx >> 6, cc = idx & 63;        // r = n-local, cc = ch-local
    op[(size_t)r*C_ + cc] = tile[cc][r];
  }
}

// ---------------- gram: G[b,h][c][d] += sum_n q[c][n]*k[d][n] ----------------
__global__ __launch_bounds__(256) void k_gram(const unsigned short* __restrict__ dwb,
                                              float* __restrict__ G){
  __shared__ alignas(16) unsigned char smem[50688];
  unsigned short (*qs)[264] = (unsigned short(*)[264])smem;
  unsigned short (*ks)[264] = (unsigned short(*)[264])(smem + 48*264*2);
  float* red = (float*)smem;                 // reused after final barrier (36864 B <= 50688)
  const int sl = blockIdx.x & 15;
  const int h  = (blockIdx.x >> 4) & 3;
  const int b  = blockIdx.x >> 6;
  const int n0 = sl * 1024;
  const unsigned short* qp = dwb + ((size_t)(b*C3_ +       h*CHD_))*HW_;
  const unsigned short* kp = dwb + ((size_t)(b*C3_ + 192 + h*CHD_))*HW_;
  const int t = threadIdx.x, lane = t & 63, wv = t >> 6;
  const int g = lane >> 4, rr = lane & 15;
  f4 acc[3][3];
  #pragma unroll
  for(int i=0;i<3;i++)
    #pragma unroll
    for(int j=0;j<3;j++) acc[i][j] = f4{0,0,0,0};
  for(int chunk=0; chunk<4; chunk++){
    const int nb = n0 + chunk*256;
    if(chunk) __syncthreads();
    #pragma unroll
    for(int i=0;i<6;i++){
      int idx = t + (i<<8);
      int r = idx >> 5, o8 = idx & 31;
      *(bfrag*)&qs[r][o8*8] = *(const bfrag*)(qp + (size_t)r*HW_ + nb + o8*8);
    }
    #pragma unroll
    for(int i=0;i<6;i++){
      int idx = t + (i<<8);
      int r = idx >> 5, o8 = idx & 31;
      *(bfrag*)&ks[r][o8*8] = *(const bfrag*)(kp + (size_t)r*HW_ + nb + o8*8);
    }
    __syncthreads();
    #pragma unroll
    for(int s=0; s<2; s++){
      const int kloc = wv*64 + s*32 + g*8;
      bfrag a0 = *(const bfrag*)&qs[ 0 + rr][kloc];
      bfrag a1 = *(const bfrag*)&qs[16 + rr][kloc];
      bfrag a2 = *(const bfrag*)&qs[32 + rr][kloc];
      bfrag b0 = *(const bfrag*)&ks[ 0 + rr][kloc];
      bfrag b1 = *(const bfrag*)&ks[16 + rr][kloc];
      bfrag b2 = *(const bfrag*)&ks[32 + rr][kloc];
      acc[0][0] = __builtin_amdgcn_mfma_f32_16x16x32_bf16(a0, b0, acc[0][0], 0,0,0);
      acc[0][1] = __builtin_amdgcn_mfma_f32_16x16x32_bf16(a0, b1, acc[0][1], 0,0,0);
      acc[0][2] = __builtin_amdgcn_mfma_f32_16x16x32_bf16(a0, b2, acc[0][2], 0,0,0);
      acc[1][0] = __builtin_amdgcn_mfma_f32_16x16x32_bf16(a1, b0, acc[1][0], 0,0,0);
      acc[1][1] = __builtin_amdgcn_mfma_f32_16x16x32_bf16(a1, b1, acc[1][1], 0,0,0);
      acc[1][2] = __builtin_amdgcn_mfma_f32_16x16x32_bf16(a1, b2, acc[1][2], 0,0,0);
      acc[2][0] = __builtin_amdgcn_mfma_f32_16x16x32_bf16(a2, b0, acc[2][0], 0,0,0);
      acc[2][1] = __builtin_amdgcn_mfma_f32_16x16x32_bf16(a2, b1, acc[2][1], 0,0,0);
      acc[2][2] = __builtin_amdgcn_mfma_f32_16x16x32_bf16(a2, b2, acc[2][2], 0,0,0);
    }
  }
  __syncthreads();
  #pragma unroll
  for(int i=0;i<3;i++)
    #pragma unroll
    for(int j=0;j<3;j++)
      #pragma unroll
      for(int r=0;r<4;r++)
        red[wv*2304 + (i*16 + g*4 + r)*48 + j*16 + rr] = acc[i][j][r];
  __syncthreads();
  float* gp = G + (size_t)(b*4 + h)*2304;
  #pragma unroll
  for(int i=0;i<9;i++){
    int e = t + (i<<8);
    float s = red[e] + red[2304 + e] + red[4608 + e] + red[6912 + e];
    atomicAdd(&gp[e], s);
  }
}

// ---------------- softmax over d with L2-norm scaling + temperature ----------------
__global__ __launch_bounds__(64) void k_softmax(const float* __restrict__ G,
                                                const float* __restrict__ norm2,
                                                const float* __restrict__ temp,
                                                float* __restrict__ attnb){
  const int h = blockIdx.x & 3, b = blockIdx.x >> 2;
  const int t = threadIdx.x;
  if(t < 48){
    const float* gr = G + (size_t)(b*4 + h)*2304 + t*48;
    float qn = sqrtf(norm2[b*384 + h*CHD_ + t]);
    float invq = temp[h] / fmaxf(qn, 1e-12f);
    float l[48];
    float mx = -1e30f;
    #pragma unroll
    for(int d=0; d<48; d++){
      float kn = sqrtf(norm2[b*384 + 192 + h*CHD_ + d]);
      l[d] = gr[d] * invq / fmaxf(kn, 1e-12f);
      mx = fmaxf(mx, l[d]);
    }
    float sum = 0.f;
    #pragma unroll
    for(int d=0; d<48; d++){ float e = expf(l[d] - mx); l[d] = e; sum += e; }
    float inv = 1.f / sum;
    float* ar = attnb + (size_t)(b*4 + h)*2304 + t*48;
    #pragma unroll
    for(int d=0; d<48; d++) ar[d] = l[d] * inv;
  }
}

// ---------------- fold: M_b[oc][h*48+d] = sum_c projw[oc][h*48+c] * attn[h][c][d] ----------------
__global__ __launch_bounds__(256) void k_fold(const float* __restrict__ attnb,
                                              const float* __restrict__ projw,
                                              unsigned short* __restrict__ Mb){
  const int og = blockIdx.x & 7, b = blockIdx.x >> 3;
  const int t = threadIdx.x;
  __shared__ float at[4*48*48];
  #pragma unroll
  for(int i=0;i<36;i++){
    int e = t + (i<<8);
    at[e] = attnb[(size_t)b*9216 + e];
  }
  __syncthreads();
  #pragma unroll
  for(int i=0;i<18;i++){
    int e = t + (i<<8);                 // 0..4607
    int oc = og*24 + e/192, cgc = e%192;
    int h = cgc/48, d = cgc%48;
    const float* wr = projw + oc*192 + h*48;
    const float* ac = &at[h*2304 + d];
    float s = 0.f;
    #pragma unroll
    for(int cc=0; cc<48; cc++) s += wr[cc] * ac[cc*48];
    Mb[((size_t)b*192 + oc)*192 + cgc] = f2bf(s);
  }
}

// ---------------- out GEMM: out[b][oc][n] = sum_k M_b[oc][k] * vT[n][k] ----------------
__global__ __launch_bounds__(256) void k_out_gemm(const unsigned short* __restrict__ vT,
                                                  const unsigned short* __restrict__ Mb,
                                                  float* __restrict__ out){
  __shared__ alignas(16) unsigned short vs[128][200];
  __shared__ alignas(16) unsigned short ms[64][200];
  const int nt = blockIdx.x & 127, b = blockIdx.x >> 7;
  const int t = threadIdx.x, lane = t & 63, wv = t >> 6;
  const int g = lane >> 4, rr = lane & 15;
  const unsigned short* vp = vT + ((size_t)(b*HW_ + nt*128))*C_;
  #pragma unroll
  for(int i=0;i<12;i++){
    int idx = t + (i<<8);
    int r = idx/24, c8 = idx%24;
    *(bfrag*)&vs[r][c8*8] = *(const bfrag*)(vp + (size_t)r*C_ + c8*8);
  }
  const unsigned short* mp = Mb + (size_t)b*192*192;
  float* op = out + (size_t)b*C_*HW_ + nt*128;
  for(int ct=0; ct<3; ct++){
    if(ct) __syncthreads();
    #pragma unroll
    for(int i=0;i<6;i++){
      int idx = t + (i<<8);
      int r = idx/24, c8 = idx%24;
      *(bfrag*)&ms[r][c8*8] = *(const bfrag*)(mp + (size_t)(ct*64 + r)*192 + c8*8);
    }
    __syncthreads();
    f4 acc[8];
    #pragma unroll
    for(int j=0;j<8;j++) acc[j] = f4{0,0,0,0};
    #pragma unroll
    for(int kk=0; kk<6; kk++){
      const int ko = kk*32 + g*8;
      bfrag a = *(const bfrag*)&ms[wv*16 + rr][ko];
      #pragma unroll
      for(int j=0;j<8;j++){
        bfrag bb = *(const bfrag*)&vs[j*16 + rr][ko];
        acc[j] = __builtin_amdgcn_mfma_f32_16x16x32_bf16(a, bb, acc[j], 0,0,0);
      }
    }
    #pragma unroll
    for(int j=0;j<8;j++)
      #pragma unroll
      for(int r=0;r<4;r++){
        int oc = ct*64 + wv*16 + g*4 + r;
        op[(size_t)oc*HW_ + j*16 + rr] = acc[j][r];
      }
  }
}

// ---------------- workspace layout (bytes) ----------------
#define OFF_XBT   0ULL                     // 50331648  (aliased by vT after qkv GEMM)
#define OFF_WB    50331648ULL              // 221184
#define OFF_QKVB  50552832ULL              // 150994944
#define OFF_DWB   201547776ULL             // 150994944
#define OFF_G     352542720ULL             // 294912
#define OFF_N2    352837632ULL             // 12288
#define OFF_ATTN  352849920ULL             // 294912
#define OFF_MB    353144832ULL             // 589824  -> total 353734656

extern "C" void kernel_launch(void* const* d_in, const int* in_sizes, int n_in,
                              void* d_out, int out_size, void* d_ws, size_t ws_size,
                              hipStream_t stream) {
  const float* x     = (const float*)d_in[0];
  const float* qkvw  = (const float*)d_in[1];
  const float* dww   = (const float*)d_in[2];
  const float* projw = (const float*)d_in[3];
  const float* temp  = (const float*)d_in[4];
  float* out = (float*)d_out;
  char* ws = (char*)d_ws;

  unsigned short* xbT  = (unsigned short*)(ws + OFF_XBT);
  unsigned short* vTT  = (unsigned short*)(ws + OFF_XBT);   // alias: xbT dead before vT written
  unsigned short* wb   = (unsigned short*)(ws + OFF_WB);
  unsigned short* qkvb = (unsigned short*)(ws + OFF_QKVB);
  unsigned short* dwb  = (unsigned short*)(ws + OFF_DWB);
  float* G     = (float*)(ws + OFF_G);
  float* n2    = (float*)(ws + OFF_N2);
  float* attnb = (float*)(ws + OFF_ATTN);
  unsigned short* Mb = (unsigned short*)(ws + OFF_MB);

  k_init<<<300, 256, 0, stream>>>(G, 76800);                 // G + n2 contiguous
  k_conv_w<<<128, 256, 0, stream>>>(qkvw, wb, C3_*C_);
  k_transpose_x<<<6144, 256, 0, stream>>>(x, xbT);
  k_qkv_gemm<<<2048, 256, 0, stream>>>(xbT, wb, qkvb);
  k_dw<<<18432, 256, 0, stream>>>(qkvb, dww, dwb, n2);
  k_transpose_v<<<6144, 256, 0, stream>>>(dwb, vTT);
  k_gram<<<512, 256, 0, stream>>>(dwb, G);
  k_softmax<<<32, 64, 0, stream>>>(G, n2, temp, attnb);
  k_fold<<<64, 256, 0, stream>>>(attnb, projw, Mb);
  k_out_gemm<<<1024, 256, 0, stream>>>(vTT, Mb, out);
}

// Round 5
// 385.624 us; speedup vs baseline: 1.2230x; 1.0289x over previous
//
#include <hip/hip_runtime.h>

// Pipeline for XCA channel attention (B=8, C=192, HW=128x128, heads=4, ch=48):
//  k_init        : zero G + norm2 accumulators
//  k_conv_w      : qkv_w fp32 -> bf16 [576][192]
//  k_transpose_x : x [b][192][HW] fp32 -> xbT [b][HW][192] bf16 (NHWC, K-contig for MFMA B-frags)
//  k_qkv_gemm    : qkv[b] = Wqkv(576x192) @ x[b](192xHW); B-frags register-resident, A streamed
//  k_dw          : depthwise 3x3 pad1, 2 rows/thread in registers + shfl halo; fused q/k sum-sq
//  k_transpose_v : v channels -> vT [b][HW][192] bf16
//  k_gram        : G[b,h] = q @ k^T (48x48, K=HW), K-split across 16 blocks, MFMA + atomicAdd
//  k_softmax     : attn = softmax(G/(|q||k|) * temperature)
//  k_fold        : M_b = Wproj @ blockdiag(attn)  (192x192 per batch, fp32 -> bf16)
//  k_out_gemm    : out[b] = M_b @ v[b]  (fuses attn@v and proj conv), fp32 out

#define B_    8
#define C_    192
#define C3_   576
#define IMG_  128
#define HW_   16384
#define HEADS_ 4
#define CHD_  48

typedef short bfrag __attribute__((ext_vector_type(8)));
typedef float f4 __attribute__((ext_vector_type(4)));

__device__ __forceinline__ unsigned short f2bf(float f){
  unsigned int u = __builtin_bit_cast(unsigned int, f);
  u += 0x7fffu + ((u >> 16) & 1u);          // round-to-nearest-even
  return (unsigned short)(u >> 16);
}
__device__ __forceinline__ float bf2f(unsigned short h){
  unsigned int u = ((unsigned int)h) << 16;
  return __builtin_bit_cast(float, u);
}

// ---------------- init: zero G (8*4*48*48) + norm2 (8*384) ----------------
__global__ __launch_bounds__(256) void k_init(float* __restrict__ p, int n){
  int i = blockIdx.x*256 + threadIdx.x;
  if(i < n) p[i] = 0.f;
}

// ---------------- W conversion ----------------
__global__ __launch_bounds__(256) void k_conv_w(const float* __restrict__ w,
                                                unsigned short* __restrict__ o, int n){
  for(int i = blockIdx.x*256 + threadIdx.x; i < n; i += gridDim.x*256)
    o[i] = f2bf(w[i]);
}

// ---------------- x transpose: [b][192][HW] f32 -> [b][HW][192] bf16 ----------------
__global__ __launch_bounds__(256) void k_transpose_x(const float* __restrict__ x,
                                                     unsigned short* __restrict__ xbT){
  __shared__ float tile[64][65];
  const int nt = blockIdx.x & 255;
  const int cg = (blockIdx.x >> 8) % 3;
  const int b  = blockIdx.x / 768;
  const float* xp = x + ((size_t)(b*C_ + cg*64))*HW_ + nt*64;
  #pragma unroll
  for(int i=0;i<16;i++){
    int idx = threadIdx.x + (i<<8);
    int r = idx >> 6, cc = idx & 63;        // r = ch-local, cc = n-local
    tile[r][cc] = xp[(size_t)r*HW_ + cc];
  }
  __syncthreads();
  unsigned short* op = xbT + ((size_t)(b*HW_ + nt*64))*C_ + cg*64;
  #pragma unroll
  for(int i=0;i<16;i++){
    int idx = threadIdx.x + (i<<8);
    int r = idx >> 6, cc = idx & 63;        // r = n-local, cc = ch-local
    op[(size_t)r*C_ + cc] = f2bf(tile[cc][r]);
  }
}

// ---------------- qkv GEMM: D[oc][n] = W[oc][k] * xT[n][k] ----------------
// B-fragments (x tile) register-resident across all 9 oc-tiles; A streamed via LDS.
// XOR-swizzled granules: logical granule gr (16B) of row r stored at slot (gr&24)|((gr^r)&7).
__global__ __launch_bounds__(256, 3) void k_qkv_gemm(const unsigned short* __restrict__ xbT,
                                                     const unsigned short* __restrict__ wb,
                                                     unsigned short* __restrict__ qkvb){
  __shared__ alignas(16) unsigned short xs[64][192];
  __shared__ alignas(16) unsigned short wsl[64][192];
  const int nt = blockIdx.x & 255, b = blockIdx.x >> 8;
  const int t = threadIdx.x, lane = t & 63, wv = t >> 6;
  const int g = lane >> 4, rr = lane & 15;
  const unsigned short* xp = xbT + ((size_t)(b*HW_ + nt*64))*C_;
  #pragma unroll
  for(int i=0;i<6;i++){
    int idx = t + (i<<8);
    int r = idx/24, c8 = idx%24;
    int slot = (c8 & 24) | ((c8 ^ r) & 7);
    *(bfrag*)&xs[r][slot*8] = *(const bfrag*)(xp + (size_t)r*C_ + c8*8);
  }
  __syncthreads();
  // hoist B-frags: 4 px-groups x 6 k-slices, held in registers for the whole kernel
  bfrag bf[4][6];
  #pragma unroll
  for(int j=0;j<4;j++){
    #pragma unroll
    for(int kk=0;kk<6;kk++){
      int row = j*16 + rr;
      int gr = kk*4 + g;
      int slot = (gr & 24) | ((gr ^ row) & 7);
      bf[j][kk] = *(const bfrag*)&xs[row][slot*8];
    }
  }
  for(int ct=0; ct<9; ct++){
    if(ct) __syncthreads();
    const unsigned short* wp = wb + (size_t)(ct*64)*C_;
    #pragma unroll
    for(int i=0;i<6;i++){
      int idx = t + (i<<8);
      int r = idx/24, c8 = idx%24;
      int slot = (c8 & 24) | ((c8 ^ r) & 7);
      *(bfrag*)&wsl[r][slot*8] = *(const bfrag*)(wp + (size_t)r*C_ + c8*8);
    }
    __syncthreads();
    f4 acc0={0,0,0,0}, acc1={0,0,0,0}, acc2={0,0,0,0}, acc3={0,0,0,0};
    #pragma unroll
    for(int kk=0; kk<6; kk++){
      const int row = wv*16 + rr;
      const int gr = kk*4 + g;
      const int slot = (gr & 24) | ((gr ^ row) & 7);
      bfrag a = *(const bfrag*)&wsl[row][slot*8];
      acc0 = __builtin_amdgcn_mfma_f32_16x16x32_bf16(a, bf[0][kk], acc0, 0,0,0);
      acc1 = __builtin_amdgcn_mfma_f32_16x16x32_bf16(a, bf[1][kk], acc1, 0,0,0);
      acc2 = __builtin_amdgcn_mfma_f32_16x16x32_bf16(a, bf[2][kk], acc2, 0,0,0);
      acc3 = __builtin_amdgcn_mfma_f32_16x16x32_bf16(a, bf[3][kk], acc3, 0,0,0);
    }
    // D: col = lane&15 (n), row = (lane>>4)*4 + reg (oc)
    unsigned short* op = qkvb + ((size_t)(b*C3_ + ct*64 + wv*16 + g*4))*HW_ + nt*64 + rr;
    #pragma unroll
    for(int r=0;r<4;r++){
      op[(size_t)r*HW_ +  0] = f2bf(acc0[r]);
      op[(size_t)r*HW_ + 16] = f2bf(acc1[r]);
      op[(size_t)r*HW_ + 32] = f2bf(acc2[r]);
      op[(size_t)r*HW_ + 48] = f2bf(acc3[r]);
    }
  }
}

// ---------------- depthwise 3x3, pad 1; 2 rows/thread, register rows + shfl halo ----------------
// block: 256 thr = 4 waves; wave = 4 row-pairs x 128 px (16 lanes/row, 8 px/thread/row)
// block covers 32 rows of one (b,c); grid: 4 row-tiles x 576 ch x 8 batch = 18432 blocks
__global__ __launch_bounds__(256) void k_dw(const unsigned short* __restrict__ qkvb,
                                            const float* __restrict__ dww,
                                            unsigned short* __restrict__ dwb,
                                            float* __restrict__ norm2){
  const int rt = blockIdx.x & 3;
  const int c  = (blockIdx.x >> 2) % C3_;
  const int b  = blockIdx.x / (4*C3_);
  const int t = threadIdx.x, lane = t & 63, wv = t >> 6;
  const int x0 = (lane & 15) << 3;
  const int row0 = rt*32 + wv*8 + (lane >> 4)*2;     // first of 2 output rows (even, <=126)
  const unsigned short* ip = qkvb + ((size_t)(b*C3_ + c))*HW_;
  const float w0=dww[c*9+0], w1=dww[c*9+1], w2=dww[c*9+2],
              w3=dww[c*9+3], w4=dww[c*9+4], w5=dww[c*9+5],
              w6=dww[c*9+6], w7=dww[c*9+7], w8=dww[c*9+8];

  float r0[8], r1[8], r2[8], r3[8];
  if(row0 > 0){
    bfrag v = *(const bfrag*)(ip + (size_t)(row0-1)*IMG_ + x0);
    #pragma unroll
    for(int j=0;j<8;j++) r0[j] = bf2f((unsigned short)v[j]);
  } else {
    #pragma unroll
    for(int j=0;j<8;j++) r0[j] = 0.f;
  }
  {
    bfrag v = *(const bfrag*)(ip + (size_t)row0*IMG_ + x0);
    #pragma unroll
    for(int j=0;j<8;j++) r1[j] = bf2f((unsigned short)v[j]);
  }
  {
    bfrag v = *(const bfrag*)(ip + (size_t)(row0+1)*IMG_ + x0);
    #pragma unroll
    for(int j=0;j<8;j++) r2[j] = bf2f((unsigned short)v[j]);
  }
  if(row0 < 126){
    bfrag v = *(const bfrag*)(ip + (size_t)(row0+2)*IMG_ + x0);
    #pragma unroll
    for(int j=0;j<8;j++) r3[j] = bf2f((unsigned short)v[j]);
  } else {
    #pragma unroll
    for(int j=0;j<8;j++) r3[j] = 0.f;
  }

  const int lm = (lane + 63) & 63, lp = (lane + 1) & 63;
  const bool atL = (x0 == 0), atR = (x0 == 120);
  float l0 = __shfl(r0[7], lm), rgt0 = __shfl(r0[0], lp);
  float l1 = __shfl(r1[7], lm), rgt1 = __shfl(r1[0], lp);
  float l2 = __shfl(r2[7], lm), rgt2 = __shfl(r2[0], lp);
  float l3 = __shfl(r3[7], lm), rgt3 = __shfl(r3[0], lp);
  if(atL){ l0 = 0.f; l1 = 0.f; l2 = 0.f; l3 = 0.f; }
  if(atR){ rgt0 = 0.f; rgt1 = 0.f; rgt2 = 0.f; rgt3 = 0.f; }

  float accA[8], accB[8];
  #pragma unroll
  for(int j=0;j<8;j++){ accA[j] = 0.f; accB[j] = 0.f; }

  // out row0: taps rows r0,r1,r2 ; out row0+1: taps rows r1,r2,r3
  {
    accA[0] += w0*l0 + w1*r0[0] + w2*r0[1];
    #pragma unroll
    for(int j=1;j<7;j++) accA[j] += w0*r0[j-1] + w1*r0[j] + w2*r0[j+1];
    accA[7] += w0*r0[6] + w1*r0[7] + w2*rgt0;
  }
  {
    accA[0] += w3*l1 + w4*r1[0] + w5*r1[1];
    accB[0] += w0*l1 + w1*r1[0] + w2*r1[1];
    #pragma unroll
    for(int j=1;j<7;j++){
      accA[j] += w3*r1[j-1] + w4*r1[j] + w5*r1[j+1];
      accB[j] += w0*r1[j-1] + w1*r1[j] + w2*r1[j+1];
    }
    accA[7] += w3*r1[6] + w4*r1[7] + w5*rgt1;
    accB[7] += w0*r1[6] + w1*r1[7] + w2*rgt1;
  }
  {
    accA[0] += w6*l2 + w7*r2[0] + w8*r2[1];
    accB[0] += w3*l2 + w4*r2[0] + w5*r2[1];
    #pragma unroll
    for(int j=1;j<7;j++){
      accA[j] += w6*r2[j-1] + w7*r2[j] + w8*r2[j+1];
      accB[j] += w3*r2[j-1] + w4*r2[j] + w5*r2[j+1];
    }
    accA[7] += w6*r2[6] + w7*r2[7] + w8*rgt2;
    accB[7] += w3*r2[6] + w4*r2[7] + w5*rgt2;
  }
  {
    accB[0] += w6*l3 + w7*r3[0] + w8*r3[1];
    #pragma unroll
    for(int j=1;j<7;j++) accB[j] += w6*r3[j-1] + w7*r3[j] + w8*r3[j+1];
    accB[7] += w6*r3[6] + w7*r3[7] + w8*rgt3;
  }

  unsigned short* op = dwb + ((size_t)(b*C3_ + c))*HW_ + (size_t)row0*IMG_ + x0;
  bfrag ovA, ovB;
  float ssq = 0.f;
  #pragma unroll
  for(int j=0;j<8;j++){
    unsigned short oa = f2bf(accA[j]);
    unsigned short ob = f2bf(accB[j]);
    ovA[j] = (short)oa; ovB[j] = (short)ob;
    float sa = bf2f(oa), sb = bf2f(ob);   // norms from stored bf16 -> consistent with gram inputs
    ssq += sa*sa + sb*sb;
  }
  *(bfrag*)op = ovA;
  *(bfrag*)(op + IMG_) = ovB;

  if(c < 384){
    #pragma unroll
    for(int off=32; off; off>>=1) ssq += __shfl_down(ssq, off, 64);
    if(lane == 0) atomicAdd(&norm2[b*384 + c], ssq);
  }
}

// ---------------- v transpose: dwb v-part [192][HW] -> vT [HW][192] bf16 ----------------
__global__ __launch_bounds__(256) void k_transpose_v(const unsigned short* __restrict__ dwb,
                                                     unsigned short* __restrict__ vT){
  __shared__ unsigned short tile[64][65];
  const int nt = blockIdx.x & 255;
  const int cg = (blockIdx.x >> 8) % 3;
  const int b  = blockIdx.x / 768;
  const unsigned short* ip = dwb + ((size_t)(b*C3_ + 384 + cg*64))*HW_ + nt*64;
  #pragma unroll
  for(int i=0;i<16;i++){
    int idx = threadIdx.x + (i<<8);
    int r = idx >> 6, cc = idx & 63;        // r = ch-local, cc = n-local
    tile[r][cc] = ip[(size_t)r*HW_ + cc];
  }
  __syncthreads();
  unsigned short* op = vT + ((size_t)(b*HW_ + nt*64))*C_ + cg*64;
  #pragma unroll
  for(int i=0;i<16;i++){
    int idx = threadIdx.x + (i<<8);
    int r = idx >> 6, cc = idx & 63;        // r = n-local, cc = ch-local
    op[(size_t)r*C_ + cc] = tile[cc][r];
  }
}

// ---------------- gram: G[b,h][c][d] += sum_n q[c][n]*k[d][n] ----------------
__global__ __launch_bounds__(256) void k_gram(const unsigned short* __restrict__ dwb,
                                              float* __restrict__ G){
  __shared__ alignas(16) unsigned char smem[50688];
  unsigned short (*qs)[264] = (unsigned short(*)[264])smem;
  unsigned short (*ks)[264] = (unsigned short(*)[264])(smem + 48*264*2);
  float* red = (float*)smem;                 // reused after final barrier (36864 B <= 50688)
  const int sl = blockIdx.x & 15;
  const int h  = (blockIdx.x >> 4) & 3;
  const int b  = blockIdx.x >> 6;
  const int n0 = sl * 1024;
  const unsigned short* qp = dwb + ((size_t)(b*C3_ +       h*CHD_))*HW_;
  const unsigned short* kp = dwb + ((size_t)(b*C3_ + 192 + h*CHD_))*HW_;
  const int t = threadIdx.x, lane = t & 63, wv = t >> 6;
  const int g = lane >> 4, rr = lane & 15;
  f4 acc[3][3];
  #pragma unroll
  for(int i=0;i<3;i++)
    #pragma unroll
    for(int j=0;j<3;j++) acc[i][j] = f4{0,0,0,0};
  for(int chunk=0; chunk<4; chunk++){
    const int nb = n0 + chunk*256;
    if(chunk) __syncthreads();
    #pragma unroll
    for(int i=0;i<6;i++){
      int idx = t + (i<<8);
      int r = idx >> 5, o8 = idx & 31;
      *(bfrag*)&qs[r][o8*8] = *(const bfrag*)(qp + (size_t)r*HW_ + nb + o8*8);
    }
    #pragma unroll
    for(int i=0;i<6;i++){
      int idx = t + (i<<8);
      int r = idx >> 5, o8 = idx & 31;
      *(bfrag*)&ks[r][o8*8] = *(const bfrag*)(kp + (size_t)r*HW_ + nb + o8*8);
    }
    __syncthreads();
    #pragma unroll
    for(int s=0; s<2; s++){
      const int kloc = wv*64 + s*32 + g*8;
      bfrag a0 = *(const bfrag*)&qs[ 0 + rr][kloc];
      bfrag a1 = *(const bfrag*)&qs[16 + rr][kloc];
      bfrag a2 = *(const bfrag*)&qs[32 + rr][kloc];
      bfrag b0 = *(const bfrag*)&ks[ 0 + rr][kloc];
      bfrag b1 = *(const bfrag*)&ks[16 + rr][kloc];
      bfrag b2 = *(const bfrag*)&ks[32 + rr][kloc];
      acc[0][0] = __builtin_amdgcn_mfma_f32_16x16x32_bf16(a0, b0, acc[0][0], 0,0,0);
      acc[0][1] = __builtin_amdgcn_mfma_f32_16x16x32_bf16(a0, b1, acc[0][1], 0,0,0);
      acc[0][2] = __builtin_amdgcn_mfma_f32_16x16x32_bf16(a0, b2, acc[0][2], 0,0,0);
      acc[1][0] = __builtin_amdgcn_mfma_f32_16x16x32_bf16(a1, b0, acc[1][0], 0,0,0);
      acc[1][1] = __builtin_amdgcn_mfma_f32_16x16x32_bf16(a1, b1, acc[1][1], 0,0,0);
      acc[1][2] = __builtin_amdgcn_mfma_f32_16x16x32_bf16(a1, b2, acc[1][2], 0,0,0);
      acc[2][0] = __builtin_amdgcn_mfma_f32_16x16x32_bf16(a2, b0, acc[2][0], 0,0,0);
      acc[2][1] = __builtin_amdgcn_mfma_f32_16x16x32_bf16(a2, b1, acc[2][1], 0,0,0);
      acc[2][2] = __builtin_amdgcn_mfma_f32_16x16x32_bf16(a2, b2, acc[2][2], 0,0,0);
    }
  }
  __syncthreads();
  #pragma unroll
  for(int i=0;i<3;i++)
    #pragma unroll
    for(int j=0;j<3;j++)
      #pragma unroll
      for(int r=0;r<4;r++)
        red[wv*2304 + (i*16 + g*4 + r)*48 + j*16 + rr] = acc[i][j][r];
  __syncthreads();
  float* gp = G + (size_t)(b*4 + h)*2304;
  #pragma unroll
  for(int i=0;i<9;i++){
    int e = t + (i<<8);
    float s = red[e] + red[2304 + e] + red[4608 + e] + red[6912 + e];
    atomicAdd(&gp[e], s);
  }
}

// ---------------- softmax over d with L2-norm scaling + temperature ----------------
__global__ __launch_bounds__(64) void k_softmax(const float* __restrict__ G,
                                                const float* __restrict__ norm2,
                                                const float* __restrict__ temp,
                                                float* __restrict__ attnb){
  const int h = blockIdx.x & 3, b = blockIdx.x >> 2;
  const int t = threadIdx.x;
  if(t < 48){
    const float* gr = G + (size_t)(b*4 + h)*2304 + t*48;
    float qn = sqrtf(norm2[b*384 + h*CHD_ + t]);
    float invq = temp[h] / fmaxf(qn, 1e-12f);
    float l[48];
    float mx = -1e30f;
    #pragma unroll
    for(int d=0; d<48; d++){
      float kn = sqrtf(norm2[b*384 + 192 + h*CHD_ + d]);
      l[d] = gr[d] * invq / fmaxf(kn, 1e-12f);
      mx = fmaxf(mx, l[d]);
    }
    float sum = 0.f;
    #pragma unroll
    for(int d=0; d<48; d++){ float e = expf(l[d] - mx); l[d] = e; sum += e; }
    float inv = 1.f / sum;
    float* ar = attnb + (size_t)(b*4 + h)*2304 + t*48;
    #pragma unroll
    for(int d=0; d<48; d++) ar[d] = l[d] * inv;
  }
}

// ---------------- fold: M_b[oc][h*48+d] = sum_c projw[oc][h*48+c] * attn[h][c][d] ----------------
__global__ __launch_bounds__(256) void k_fold(const float* __restrict__ attnb,
                                              const float* __restrict__ projw,
                                              unsigned short* __restrict__ Mb){
  const int og = blockIdx.x & 7, b = blockIdx.x >> 3;
  const int t = threadIdx.x;
  __shared__ float at[4*48*48];
  #pragma unroll
  for(int i=0;i<36;i++){
    int e = t + (i<<8);
    at[e] = attnb[(size_t)b*9216 + e];
  }
  __syncthreads();
  #pragma unroll
  for(int i=0;i<18;i++){
    int e = t + (i<<8);                 // 0..4607
    int oc = og*24 + e/192, cgc = e%192;
    int h = cgc/48, d = cgc%48;
    const float* wr = projw + oc*192 + h*48;
    const float* ac = &at[h*2304 + d];
    float s = 0.f;
    #pragma unroll
    for(int cc=0; cc<48; cc++) s += wr[cc] * ac[cc*48];
    Mb[((size_t)b*192 + oc)*192 + cgc] = f2bf(s);
  }
}

// ---------------- out GEMM: out[b][oc][n] = sum_k M_b[oc][k] * vT[n][k] ----------------
__global__ __launch_bounds__(256) void k_out_gemm(const unsigned short* __restrict__ vT,
                                                  const unsigned short* __restrict__ Mb,
                                                  float* __restrict__ out){
  __shared__ alignas(16) unsigned short vs[128][200];
  __shared__ alignas(16) unsigned short ms[64][200];
  const int nt = blockIdx.x & 127, b = blockIdx.x >> 7;
  const int t = threadIdx.x, lane = t & 63, wv = t >> 6;
  const int g = lane >> 4, rr = lane & 15;
  const unsigned short* vp = vT + ((size_t)(b*HW_ + nt*128))*C_;
  #pragma unroll
  for(int i=0;i<12;i++){
    int idx = t + (i<<8);
    int r = idx/24, c8 = idx%24;
    *(bfrag*)&vs[r][c8*8] = *(const bfrag*)(vp + (size_t)r*C_ + c8*8);
  }
  const unsigned short* mp = Mb + (size_t)b*192*192;
  float* op = out + (size_t)b*C_*HW_ + nt*128;
  for(int ct=0; ct<3; ct++){
    if(ct) __syncthreads();
    #pragma unroll
    for(int i=0;i<6;i++){
      int idx = t + (i<<8);
      int r = idx/24, c8 = idx%24;
      *(bfrag*)&ms[r][c8*8] = *(const bfrag*)(mp + (size_t)(ct*64 + r)*192 + c8*8);
    }
    __syncthreads();
    f4 acc[8];
    #pragma unroll
    for(int j=0;j<8;j++) acc[j] = f4{0,0,0,0};
    #pragma unroll
    for(int kk=0; kk<6; kk++){
      const int ko = kk*32 + g*8;
      bfrag a = *(const bfrag*)&ms[wv*16 + rr][ko];
      #pragma unroll
      for(int j=0;j<8;j++){
        bfrag bb = *(const bfrag*)&vs[j*16 + rr][ko];
        acc[j] = __builtin_amdgcn_mfma_f32_16x16x32_bf16(a, bb, acc[j], 0,0,0);
      }
    }
    #pragma unroll
    for(int j=0;j<8;j++)
      #pragma unroll
      for(int r=0;r<4;r++){
        int oc = ct*64 + wv*16 + g*4 + r;
        op[(size_t)oc*HW_ + j*16 + rr] = acc[j][r];
      }
  }
}

// ---------------- workspace layout (bytes) ----------------
#define OFF_XBT   0ULL                     // 50331648  (aliased by vT after qkv GEMM)
#define OFF_WB    50331648ULL              // 221184
#define OFF_QKVB  50552832ULL              // 150994944
#define OFF_DWB   201547776ULL             // 150994944
#define OFF_G     352542720ULL             // 294912
#define OFF_N2    352837632ULL             // 12288
#define OFF_ATTN  352849920ULL             // 294912
#define OFF_MB    353144832ULL             // 589824  -> total 353734656

extern "C" void kernel_launch(void* const* d_in, const int* in_sizes, int n_in,
                              void* d_out, int out_size, void* d_ws, size_t ws_size,
                              hipStream_t stream) {
  const float* x     = (const float*)d_in[0];
  const float* qkvw  = (const float*)d_in[1];
  const float* dww   = (const float*)d_in[2];
  const float* projw = (const float*)d_in[3];
  const float* temp  = (const float*)d_in[4];
  float* out = (float*)d_out;
  char* ws = (char*)d_ws;

  unsigned short* xbT  = (unsigned short*)(ws + OFF_XBT);
  unsigned short* vTT  = (unsigned short*)(ws + OFF_XBT);   // alias: xbT dead before vT written
  unsigned short* wb   = (unsigned short*)(ws + OFF_WB);
  unsigned short* qkvb = (unsigned short*)(ws + OFF_QKVB);
  unsigned short* dwb  = (unsigned short*)(ws + OFF_DWB);
  float* G     = (float*)(ws + OFF_G);
  float* n2    = (float*)(ws + OFF_N2);
  float* attnb = (float*)(ws + OFF_ATTN);
  unsigned short* Mb = (unsigned short*)(ws + OFF_MB);

  k_init<<<300, 256, 0, stream>>>(G, 76800);                 // G + n2 contiguous
  k_conv_w<<<128, 256, 0, stream>>>(qkvw, wb, C3_*C_);
  k_transpose_x<<<6144, 256, 0, stream>>>(x, xbT);
  k_qkv_gemm<<<2048, 256, 0, stream>>>(xbT, wb, qkvb);
  k_dw<<<18432, 256, 0, stream>>>(qkvb, dww, dwb, n2);
  k_transpose_v<<<6144, 256, 0, stream>>>(dwb, vTT);
  k_gram<<<512, 256, 0, stream>>>(dwb, G);
  k_softmax<<<32, 64, 0, stream>>>(G, n2, temp, attnb);
  k_fold<<<64, 256, 0, stream>>>(attnb, projw, Mb);
  k_out_gemm<<<1024, 256, 0, stream>>>(vTT, Mb, out);
}